// Round 1
// baseline (767.419 us; speedup 1.0000x reference)
//
#include <hip/hip_runtime.h>

#define Bq 16
#define Sq 512
#define Dq 400
#define Vq 32000
#define Tq 8
#define NSq 30
#define NGq 3
#define BTq (Bq*Tq)                     // 128
#define SLICE 4096000                   // Bq*Tq*Vq, one ptr slice (elems)
#define PTR_TOTAL (30ull*SLICE)         // 122,880,000
#define GATE_TOTAL (NSq*Bq*NGq)         // 1440

// k_logits fused grid: 250 compute blocks + zero-fill blocks
#define NCOMPUTE 250
#define NZERO 1813                      // 29*SLICE/4 = 29,696,000 float4; 16384/block
#define ZPER 16384                      // float4 per zero block (64 per thread)

// k_gates fused grid: 64 compute blocks + 250 pctx-zero blocks
#define GCOMPUTE 64
#define PCTX_ZB 250                     // 250 * 4096 float4 = 1,024,000 = SLICE/4

__device__ inline float sigmoidf_(float x) { return 1.0f / (1.0f + __expf(-x)); }

__device__ inline float blockReduceSum(float v, float* red) {
    int tid = threadIdx.x;
    #pragma unroll
    for (int o = 32; o > 0; o >>= 1) v += __shfl_down(v, o, 64);
    if ((tid & 63) == 0) red[tid >> 6] = v;
    __syncthreads();
    if (tid == 0) {
        float s = red[0];
        int nw = blockDim.x >> 6;
        for (int i = 1; i < nw; i++) s += red[i];
        red[0] = s;
    }
    __syncthreads();
    float r = red[0];
    __syncthreads();
    return r;
}

__device__ inline float blockReduceMax(float v, float* red) {
    int tid = threadIdx.x;
    #pragma unroll
    for (int o = 32; o > 0; o >>= 1) v = fmaxf(v, __shfl_down(v, o, 64));
    if ((tid & 63) == 0) red[tid >> 6] = v;
    __syncthreads();
    if (tid == 0) {
        float s = red[0];
        int nw = blockDim.x >> 6;
        for (int i = 1; i < nw; i++) s = fmaxf(s, red[i]);
        red[0] = s;
    }
    __syncthreads();
    float r = red[0];
    __syncthreads();
    return r;
}

// gi = X @ w_ih^T + b_ih (128x1200), gh = h0 @ w_hh^T + b_hh (16x1200).
// blocks [0,64) = 16 b x 4 j-tiles(300). A rows 0..7 = x(t), row 8 = h0.
// blocks [64,314) zero pctx (replaces hipMemsetAsync; stream-ordered before
// k_attn's atomics). Weights read ~4x total.
__global__ __launch_bounds__(256) void k_gates(const float* __restrict__ enc_hidden,
                                               const float* __restrict__ shared_emb,
                                               const float* __restrict__ slot_emb,
                                               const float* __restrict__ w_ih,
                                               const float* __restrict__ w_hh,
                                               const float* __restrict__ b_ih,
                                               const float* __restrict__ b_hh,
                                               const int* __restrict__ trg,
                                               float* __restrict__ gi, float* __restrict__ gh,
                                               float* __restrict__ pctx) {
    int tid = threadIdx.x;
    if (blockIdx.x >= GCOMPUTE) {
        int zb = blockIdx.x - GCOMPUTE;
        float4 z = make_float4(0.0f, 0.0f, 0.0f, 0.0f);
        float4* dst = (float4*)pctx;
        size_t base = (size_t)zb * 4096 + tid;
        #pragma unroll
        for (int r = 0; r < 16; ++r) dst[base + (size_t)r * 256] = z;
        return;
    }
    __shared__ float A[9][Dq];
    __shared__ int toks[8];
    int b = blockIdx.x >> 2, jt = blockIdx.x & 3;
    if (tid < 7) toks[tid + 1] = trg[b * (NSq * Tq) + tid];
    __syncthreads();
    for (int idx = tid; idx < 900; idx += 256) {      // 9 rows x 100 float4
        int r = idx / 100, q = idx - r * 100;
        const float4* src;
        if (r == 8)      src = (const float4*)(enc_hidden + b * Dq);
        else if (r == 0) src = (const float4*)slot_emb;
        else             src = (const float4*)(shared_emb + (size_t)toks[r] * Dq);
        *(float4*)&A[r][4 * q] = src[q];
    }
    __syncthreads();
    for (int o = tid; o < 2700; o += 256) {           // 9 rows x 300 j
        int r = o / 300, jj = o - r * 300;
        int j = jt * 300 + jj;
        const float* w = (r == 8) ? w_hh : w_ih;
        const float4* w4 = (const float4*)(w + (size_t)j * Dq);
        const float4* a4 = (const float4*)&A[r][0];
        float acc = (r == 8) ? b_hh[j] : b_ih[j];
        #pragma unroll 4
        for (int q = 0; q < Dq / 4; ++q) {
            float4 wv = w4[q], av = a4[q];
            acc += av.x * wv.x + av.y * wv.y + av.z * wv.z + av.w * wv.w;
        }
        if (r == 8) gh[b * 1200 + j] = acc;
        else        gi[(b * 8 + r) * 1200 + j] = acc;
    }
}

// GRU elementwise + scores + softmax + scatter(probs->pctx) + context(RAW scores)
// + p_gen + gate0 + hT write. block=512, one per (b,t).
__global__ __launch_bounds__(512) void k_attn(const float* __restrict__ gi,
                                              const float* __restrict__ gh,
                                              const float* __restrict__ enc_hidden,
                                              const float* __restrict__ shared_emb,
                                              const float* __restrict__ slot_emb,
                                              const int* __restrict__ trg,
                                              const float* __restrict__ enc_out,
                                              const int* __restrict__ story,
                                              const float* __restrict__ w_ratio_w,
                                              const float* __restrict__ w_ratio_b,
                                              const float* __restrict__ w_gate_w,
                                              const float* __restrict__ w_gate_b,
                                              float* __restrict__ pctx, float* __restrict__ pgen,
                                              float* __restrict__ hT, float* __restrict__ out_gate) {
    __shared__ float h_l[Dq], ctx_l[Dq], x_l[Dq], sc_l[Sq], red[8];
    int bt = blockIdx.x, b = bt >> 3, t = bt & 7;
    int tid = threadIdx.x;
    if (tid < Dq) {
        int d = tid;
        float x = (t == 0) ? slot_emb[d]
                           : shared_emb[(size_t)trg[b * (NSq * Tq) + (t - 1)] * Dq + d];
        float h0 = enc_hidden[b * Dq + d];
        const float* gib = gi + bt * 1200;
        const float* ghb = gh + b * 1200;
        float r_ = sigmoidf_(gib[d] + ghb[d]);
        float z  = sigmoidf_(gib[Dq + d] + ghb[Dq + d]);
        float n  = tanhf(gib[2 * Dq + d] + r_ * ghb[2 * Dq + d]);
        float h  = (1.0f - z) * n + z * h0;
        h_l[d] = h; x_l[d] = x;
        hT[d * BTq + bt] = h;
    }
    __syncthreads();
    {   // scores: one s per thread
        const float4* e4 = (const float4*)(enc_out + ((size_t)(b * Sq + tid)) * Dq);
        float acc = 0.0f;
        for (int q = 0; q < Dq / 4; ++q) {
            float4 p = e4[q];
            int k = 4 * q;
            acc += h_l[k]*p.x + h_l[k+1]*p.y + h_l[k+2]*p.z + h_l[k+3]*p.w;
        }
        sc_l[tid] = acc;
    }
    __syncthreads();
    float myv = sc_l[tid];
    float m = blockReduceMax(myv, red);
    float e = __expf(myv - m);
    float ssum = blockReduceSum(e, red);
    // scatter prob directly (pctx pre-zeroed by k_gates zero blocks)
    atomicAdd(&pctx[(size_t)bt * Vq + story[b * Sq + tid]], e / ssum);
    // context from RAW scores
    for (int d = tid; d < Dq; d += 512) {
        float acc = 0.0f;
        #pragma unroll 8
        for (int s = 0; s < Sq; ++s)
            acc += sc_l[s] * enc_out[((size_t)(b * Sq + s)) * Dq + d];
        ctx_l[d] = acc;
    }
    __syncthreads();
    {   // p_gen = sigmoid([h,ctx,X] . w_ratio + b)
        float part = 0.0f;
        for (int i = tid; i < 1200; i += 512) {
            float v = (i < Dq) ? h_l[i] : (i < 2 * Dq ? ctx_l[i - Dq] : x_l[i - 2 * Dq]);
            part += v * w_ratio_w[i];
        }
        float tot = blockReduceSum(part, red);
        if (tid == 0) pgen[bt] = sigmoidf_(tot + w_ratio_b[0]);
    }
    if (t == 0) {
        for (int g = 0; g < NGq; ++g) {
            float part = 0.0f;
            for (int d = tid; d < Dq; d += 512) part += ctx_l[d] * w_gate_w[g * Dq + d];
            float tot = blockReduceSum(part, red);
            if (tid == 0) out_gate[b * NGq + g] = tot + w_gate_b[g];
        }
    }
}

// Fused: [0,250) logits GEMM blocks; [250,250+1813) zero ptr slices 1..29;
// last block zeroes gate slices 1..29. Zero-write BW overlaps GEMM compute.
#define TVL 128
#define CKL 40
__global__ __launch_bounds__(256) void k_logits(const float* __restrict__ hT,
                                                const float* __restrict__ emb,
                                                float* __restrict__ logits,
                                                float* __restrict__ out) {
    __shared__ float eT[CKL][132];
    __shared__ float hL[CKL][132];
    int bid = blockIdx.x;
    int tid = threadIdx.x;
    if (bid >= NCOMPUTE) {
        int zb = bid - NCOMPUTE;
        float4 z = make_float4(0.0f, 0.0f, 0.0f, 0.0f);
        if (zb < NZERO) {
            float4* dst = (float4*)(out + (size_t)SLICE);
            const size_t total = 29ull * SLICE / 4;   // 29,696,000 float4
            size_t base = (size_t)zb * ZPER + tid;
            #pragma unroll
            for (int r = 0; r < ZPER / 256; ++r) {
                size_t idx = base + (size_t)r * 256;
                if (idx < total) dst[idx] = z;
            }
        } else {
            float4* g = (float4*)(out + PTR_TOTAL + Bq * NGq);
            for (int i = tid; i < (GATE_TOTAL - Bq * NGq) / 4; i += 256) g[i] = z;
        }
        return;
    }
    int v0 = bid * TVL;
    int tx = tid & 15, ty = tid >> 4;
    float acc[8][8];
    #pragma unroll
    for (int j = 0; j < 8; ++j)
        #pragma unroll
        for (int i = 0; i < 8; ++i) acc[j][i] = 0.0f;

    for (int c = 0; c < Dq / CKL; ++c) {
        int k0 = c * CKL;
        const float4* hg = (const float4*)(hT + (size_t)k0 * BTq);
        #pragma unroll
        for (int r = 0; r < 5; ++r) {
            int idx = tid + 256 * r;
            int k = idx >> 5, c4 = idx & 31;
            float4 vd = hg[idx];
            *(float4*)&hL[k][4 * c4] = vd;
        }
        #pragma unroll
        for (int r = 0; r < 5; ++r) {
            int idx = tid + 256 * r;
            int v = idx / 10, q = idx - 10 * v;
            float4 vd = *(const float4*)(emb + (size_t)(v0 + v) * Dq + k0 + 4 * q);
            eT[4*q+0][v] = vd.x; eT[4*q+1][v] = vd.y; eT[4*q+2][v] = vd.z; eT[4*q+3][v] = vd.w;
        }
        __syncthreads();
        #pragma unroll 4
        for (int k = 0; k < CKL; ++k) {
            float4 h0 = *(const float4*)&hL[k][8 * ty];
            float4 h1 = *(const float4*)&hL[k][8 * ty + 4];
            float4 e0 = *(const float4*)&eT[k][8 * tx];
            float4 e1 = *(const float4*)&eT[k][8 * tx + 4];
            float hv[8] = {h0.x, h0.y, h0.z, h0.w, h1.x, h1.y, h1.z, h1.w};
            float ev[8] = {e0.x, e0.y, e0.z, e0.w, e1.x, e1.y, e1.z, e1.w};
            #pragma unroll
            for (int j = 0; j < 8; ++j)
                #pragma unroll
                for (int i = 0; i < 8; ++i)
                    acc[j][i] += hv[j] * ev[i];
        }
        __syncthreads();
    }
    #pragma unroll
    for (int j = 0; j < 8; ++j) {
        int bt = 8 * ty + j;
        float* dst = logits + (size_t)bt * Vq + v0 + 8 * tx;
        *(float4*)dst       = make_float4(acc[j][0], acc[j][1], acc[j][2], acc[j][3]);
        *(float4*)(dst + 4) = make_float4(acc[j][4], acc[j][5], acc[j][6], acc[j][7]);
    }
}

// fused softmax stats + combine: one block per bt row. 3 passes over a 128 KB
// row (passes 2-3 L2-hot).
__global__ __launch_bounds__(512) void k_final(const float* __restrict__ logits,
                                               const float* __restrict__ pctx,
                                               const float* __restrict__ pgen,
                                               float* __restrict__ out) {
    __shared__ float red[8];
    int bt = blockIdx.x, tid = threadIdx.x;
    const float* lr = logits + (size_t)bt * Vq;
    float m = -1e30f;
    for (int v = tid; v < Vq; v += 512) m = fmaxf(m, lr[v]);
    m = blockReduceMax(m, red);
    float s = 0.0f;
    for (int v = tid; v < Vq; v += 512) s += __expf(lr[v] - m);
    s = blockReduceSum(s, red);
    float inv = 1.0f / s, pg = pgen[bt], cg = 1.0f - pg;
    const float4* l4 = (const float4*)lr;
    const float4* p4 = (const float4*)(pctx + (size_t)bt * Vq);
    float4* o4 = (float4*)(out + (size_t)bt * Vq);
    for (int i = tid; i < Vq / 4; i += 512) {
        float4 lv = l4[i], pv = p4[i];
        o4[i] = make_float4(pg * __expf(lv.x - m) * inv + cg * pv.x,
                            pg * __expf(lv.y - m) * inv + cg * pv.y,
                            pg * __expf(lv.z - m) * inv + cg * pv.z,
                            pg * __expf(lv.w - m) * inv + cg * pv.w);
    }
}

extern "C" void kernel_launch(void* const* d_in, const int* in_sizes, int n_in,
                              void* d_out, int out_size, void* d_ws, size_t ws_size,
                              hipStream_t stream) {
    const float* enc_hidden = (const float*)d_in[0];
    const float* enc_out    = (const float*)d_in[1];
    const int*   story      = (const int*)d_in[2];
    const int*   trg        = (const int*)d_in[3];
    const float* shared_emb = (const float*)d_in[4];
    const float* slot_emb   = (const float*)d_in[5];
    const float* w_ih       = (const float*)d_in[6];
    const float* w_hh       = (const float*)d_in[7];
    const float* b_ih       = (const float*)d_in[8];
    const float* b_hh       = (const float*)d_in[9];
    const float* w_ratio_w  = (const float*)d_in[10];
    const float* w_ratio_b  = (const float*)d_in[11];
    const float* w_gate_w   = (const float*)d_in[12];
    const float* w_gate_b   = (const float*)d_in[13];

    float* out = (float*)d_out;

    // All scratch in d_ws (~33.7 MB of the ~1.97 GB workspace).
    float* ws = (float*)d_ws;
    float* logits_buf = ws;                        // 4,096,000 f
    float* pctx_buf   = ws + (size_t)SLICE;        // 4,096,000 f
    float* gi_buf     = ws + 2 * (size_t)SLICE;    // 153,600 f
    float* gh_buf     = gi_buf + 153600;           // 19,200 f
    float* hT_buf     = gh_buf + 19200;            // 51,200 f
    float* pgen_buf   = hT_buf + 51200;            // 128 f

    // pctx zeroing folded into k_gates grid (no runtime API calls in launch path)
    hipLaunchKernelGGL(k_gates, dim3(GCOMPUTE + PCTX_ZB), dim3(256), 0, stream,
                       enc_hidden, shared_emb, slot_emb, w_ih, w_hh, b_ih, b_hh, trg,
                       gi_buf, gh_buf, pctx_buf);
    hipLaunchKernelGGL(k_attn, dim3(BTq), dim3(512), 0, stream,
                       gi_buf, gh_buf, enc_hidden, shared_emb, slot_emb, trg,
                       enc_out, story, w_ratio_w, w_ratio_b, w_gate_w, w_gate_b,
                       pctx_buf, pgen_buf, hT_buf, out + PTR_TOTAL);
    // fused GEMM + zero-fill of out slices 1..29 (ptr and gate)
    hipLaunchKernelGGL(k_logits, dim3(NCOMPUTE + NZERO + 1), dim3(256), 0, stream,
                       hT_buf, shared_emb, logits_buf, out);
    hipLaunchKernelGGL(k_final, dim3(BTq), dim3(512), 0, stream,
                       logits_buf, pctx_buf, pgen_buf, out);
}

// Round 2
// 750.681 us; speedup vs baseline: 1.0223x; 1.0223x over previous
//
#include <hip/hip_runtime.h>

#define Bq 16
#define Sq 512
#define Dq 400
#define Vq 32000
#define Tq 8
#define NSq 30
#define NGq 3
#define BTq (Bq*Tq)                     // 128
#define SLICE 4096000                   // Bq*Tq*Vq, one ptr slice (elems)
#define PTR_TOTAL (30ull*SLICE)         // 122,880,000
#define GATE_TOTAL (NSq*Bq*NGq)         // 1440

// k_logits fused grid: 250 compute blocks + zero-fill blocks
#define NCOMPUTE 250
#define NZERO 1813                      // 29*SLICE/4 = 29,696,000 float4; 16384/block
#define ZPER 16384                      // float4 per zero block (64 per thread)

// k_gates fused grid: 64 compute blocks + 250 pctx-zero blocks
#define GCOMPUTE 64
#define PCTX_ZB 250                     // 250 * 4096 float4 = 1,024,000 = SLICE/4

// k_final: 8 blocks per bt row, single streaming pass
#define FBLK 8
#define FCH (Vq/FBLK)                   // 4000 v per block

__device__ inline float sigmoidf_(float x) { return 1.0f / (1.0f + __expf(-x)); }

// round-to-nearest-even f32 -> bf16 (as ushort in low 16 bits)
__device__ inline unsigned bf16rne(float x) {
    unsigned u = __float_as_uint(x);
    return (u + 0x7FFFu + ((u >> 16) & 1u)) >> 16;
}

__device__ inline float blockReduceSum(float v, float* red) {
    int tid = threadIdx.x;
    #pragma unroll
    for (int o = 32; o > 0; o >>= 1) v += __shfl_down(v, o, 64);
    if ((tid & 63) == 0) red[tid >> 6] = v;
    __syncthreads();
    if (tid == 0) {
        float s = red[0];
        int nw = blockDim.x >> 6;
        for (int i = 1; i < nw; i++) s += red[i];
        red[0] = s;
    }
    __syncthreads();
    float r = red[0];
    __syncthreads();
    return r;
}

__device__ inline float blockReduceMax(float v, float* red) {
    int tid = threadIdx.x;
    #pragma unroll
    for (int o = 32; o > 0; o >>= 1) v = fmaxf(v, __shfl_down(v, o, 64));
    if ((tid & 63) == 0) red[tid >> 6] = v;
    __syncthreads();
    if (tid == 0) {
        float s = red[0];
        int nw = blockDim.x >> 6;
        for (int i = 1; i < nw; i++) s = fmaxf(s, red[i]);
        red[0] = s;
    }
    __syncthreads();
    float r = red[0];
    __syncthreads();
    return r;
}

// gi = X @ w_ih^T + b_ih (128x1200), gh = h0 @ w_hh^T + b_hh (16x1200).
// blocks [0,64) = 16 b x 4 j-tiles(300). A rows 0..7 = x(t), row 8 = h0.
// blocks [64,314) zero pctx (stream-ordered before k_attn's atomics).
__global__ __launch_bounds__(256) void k_gates(const float* __restrict__ enc_hidden,
                                               const float* __restrict__ shared_emb,
                                               const float* __restrict__ slot_emb,
                                               const float* __restrict__ w_ih,
                                               const float* __restrict__ w_hh,
                                               const float* __restrict__ b_ih,
                                               const float* __restrict__ b_hh,
                                               const int* __restrict__ trg,
                                               float* __restrict__ gi, float* __restrict__ gh,
                                               float* __restrict__ pctx) {
    int tid = threadIdx.x;
    if (blockIdx.x >= GCOMPUTE) {
        int zb = blockIdx.x - GCOMPUTE;
        float4 z = make_float4(0.0f, 0.0f, 0.0f, 0.0f);
        float4* dst = (float4*)pctx;
        size_t base = (size_t)zb * 4096 + tid;
        #pragma unroll
        for (int r = 0; r < 16; ++r) dst[base + (size_t)r * 256] = z;
        return;
    }
    __shared__ float A[9][Dq];
    __shared__ int toks[8];
    int b = blockIdx.x >> 2, jt = blockIdx.x & 3;
    if (tid < 7) toks[tid + 1] = trg[b * (NSq * Tq) + tid];
    __syncthreads();
    for (int idx = tid; idx < 900; idx += 256) {      // 9 rows x 100 float4
        int r = idx / 100, q = idx - r * 100;
        const float4* src;
        if (r == 8)      src = (const float4*)(enc_hidden + b * Dq);
        else if (r == 0) src = (const float4*)slot_emb;
        else             src = (const float4*)(shared_emb + (size_t)toks[r] * Dq);
        *(float4*)&A[r][4 * q] = src[q];
    }
    __syncthreads();
    for (int o = tid; o < 2700; o += 256) {           // 9 rows x 300 j
        int r = o / 300, jj = o - r * 300;
        int j = jt * 300 + jj;
        const float* w = (r == 8) ? w_hh : w_ih;
        const float4* w4 = (const float4*)(w + (size_t)j * Dq);
        const float4* a4 = (const float4*)&A[r][0];
        float acc = (r == 8) ? b_hh[j] : b_ih[j];
        #pragma unroll 4
        for (int q = 0; q < Dq / 4; ++q) {
            float4 wv = w4[q], av = a4[q];
            acc += av.x * wv.x + av.y * wv.y + av.z * wv.z + av.w * wv.w;
        }
        if (r == 8) gh[b * 1200 + j] = acc;
        else        gi[(b * 8 + r) * 1200 + j] = acc;
    }
}

// GRU elementwise + scores + softmax + scatter(probs->pctx) + context(RAW scores)
// + p_gen + gate0 + hT write. block=512, one per (b,t).
__global__ __launch_bounds__(512) void k_attn(const float* __restrict__ gi,
                                              const float* __restrict__ gh,
                                              const float* __restrict__ enc_hidden,
                                              const float* __restrict__ shared_emb,
                                              const float* __restrict__ slot_emb,
                                              const int* __restrict__ trg,
                                              const float* __restrict__ enc_out,
                                              const int* __restrict__ story,
                                              const float* __restrict__ w_ratio_w,
                                              const float* __restrict__ w_ratio_b,
                                              const float* __restrict__ w_gate_w,
                                              const float* __restrict__ w_gate_b,
                                              float* __restrict__ pctx, float* __restrict__ pgen,
                                              float* __restrict__ hT, float* __restrict__ out_gate) {
    __shared__ float h_l[Dq], ctx_l[Dq], x_l[Dq], sc_l[Sq], red[8];
    int bt = blockIdx.x, b = bt >> 3, t = bt & 7;
    int tid = threadIdx.x;
    if (tid < Dq) {
        int d = tid;
        float x = (t == 0) ? slot_emb[d]
                           : shared_emb[(size_t)trg[b * (NSq * Tq) + (t - 1)] * Dq + d];
        float h0 = enc_hidden[b * Dq + d];
        const float* gib = gi + bt * 1200;
        const float* ghb = gh + b * 1200;
        float r_ = sigmoidf_(gib[d] + ghb[d]);
        float z  = sigmoidf_(gib[Dq + d] + ghb[Dq + d]);
        float n  = tanhf(gib[2 * Dq + d] + r_ * ghb[2 * Dq + d]);
        float h  = (1.0f - z) * n + z * h0;
        h_l[d] = h; x_l[d] = x;
        hT[d * BTq + bt] = h;
    }
    __syncthreads();
    {   // scores: one s per thread
        const float4* e4 = (const float4*)(enc_out + ((size_t)(b * Sq + tid)) * Dq);
        float acc = 0.0f;
        for (int q = 0; q < Dq / 4; ++q) {
            float4 p = e4[q];
            int k = 4 * q;
            acc += h_l[k]*p.x + h_l[k+1]*p.y + h_l[k+2]*p.z + h_l[k+3]*p.w;
        }
        sc_l[tid] = acc;
    }
    __syncthreads();
    float myv = sc_l[tid];
    float m = blockReduceMax(myv, red);
    float e = __expf(myv - m);
    float ssum = blockReduceSum(e, red);
    // scatter prob directly (pctx pre-zeroed by k_gates zero blocks)
    atomicAdd(&pctx[(size_t)bt * Vq + story[b * Sq + tid]], e / ssum);
    // context from RAW scores
    for (int d = tid; d < Dq; d += 512) {
        float acc = 0.0f;
        #pragma unroll 8
        for (int s = 0; s < Sq; ++s)
            acc += sc_l[s] * enc_out[((size_t)(b * Sq + s)) * Dq + d];
        ctx_l[d] = acc;
    }
    __syncthreads();
    {   // p_gen = sigmoid([h,ctx,X] . w_ratio + b)
        float part = 0.0f;
        for (int i = tid; i < 1200; i += 512) {
            float v = (i < Dq) ? h_l[i] : (i < 2 * Dq ? ctx_l[i - Dq] : x_l[i - 2 * Dq]);
            part += v * w_ratio_w[i];
        }
        float tot = blockReduceSum(part, red);
        if (tid == 0) pgen[bt] = sigmoidf_(tot + w_ratio_b[0]);
    }
    if (t == 0) {
        for (int g = 0; g < NGq; ++g) {
            float part = 0.0f;
            for (int d = tid; d < Dq; d += 512) part += ctx_l[d] * w_gate_w[g * Dq + d];
            float tot = blockReduceSum(part, red);
            if (tid == 0) out_gate[b * NGq + g] = tot + w_gate_b[g];
        }
    }
}

// Fused: [0,250) logits GEMM blocks (bf16 logits + per-block softmax partials);
// [250,250+1813) zero ptr slices 1..29; last block zeroes gate slices 1..29.
#define TVL 128
#define CKL 40
__global__ __launch_bounds__(256) void k_logits(const float* __restrict__ hT,
                                                const float* __restrict__ emb,
                                                unsigned short* __restrict__ logits,
                                                float* __restrict__ pmax,
                                                float* __restrict__ psum,
                                                float* __restrict__ out) {
    __shared__ float eT[CKL][132];
    __shared__ float hL[CKL][132];
    int bid = blockIdx.x;
    int tid = threadIdx.x;
    if (bid >= NCOMPUTE) {
        int zb = bid - NCOMPUTE;
        float4 z = make_float4(0.0f, 0.0f, 0.0f, 0.0f);
        if (zb < NZERO) {
            float4* dst = (float4*)(out + (size_t)SLICE);
            const size_t total = 29ull * SLICE / 4;   // 29,696,000 float4
            size_t base = (size_t)zb * ZPER + tid;
            #pragma unroll
            for (int r = 0; r < ZPER / 256; ++r) {
                size_t idx = base + (size_t)r * 256;
                if (idx < total) dst[idx] = z;
            }
        } else {
            float4* g = (float4*)(out + PTR_TOTAL + Bq * NGq);
            for (int i = tid; i < (GATE_TOTAL - Bq * NGq) / 4; i += 256) g[i] = z;
        }
        return;
    }
    int v0 = bid * TVL;
    int tx = tid & 15, ty = tid >> 4;
    float acc[8][8];
    #pragma unroll
    for (int j = 0; j < 8; ++j)
        #pragma unroll
        for (int i = 0; i < 8; ++i) acc[j][i] = 0.0f;

    for (int c = 0; c < Dq / CKL; ++c) {
        int k0 = c * CKL;
        const float4* hg = (const float4*)(hT + (size_t)k0 * BTq);
        #pragma unroll
        for (int r = 0; r < 5; ++r) {
            int idx = tid + 256 * r;
            int k = idx >> 5, c4 = idx & 31;
            float4 vd = hg[idx];
            *(float4*)&hL[k][4 * c4] = vd;
        }
        #pragma unroll
        for (int r = 0; r < 5; ++r) {
            int idx = tid + 256 * r;
            int v = idx / 10, q = idx - 10 * v;
            float4 vd = *(const float4*)(emb + (size_t)(v0 + v) * Dq + k0 + 4 * q);
            eT[4*q+0][v] = vd.x; eT[4*q+1][v] = vd.y; eT[4*q+2][v] = vd.z; eT[4*q+3][v] = vd.w;
        }
        __syncthreads();
        #pragma unroll 4
        for (int k = 0; k < CKL; ++k) {
            float4 h0 = *(const float4*)&hL[k][8 * ty];
            float4 h1 = *(const float4*)&hL[k][8 * ty + 4];
            float4 e0 = *(const float4*)&eT[k][8 * tx];
            float4 e1 = *(const float4*)&eT[k][8 * tx + 4];
            float hv[8] = {h0.x, h0.y, h0.z, h0.w, h1.x, h1.y, h1.z, h1.w};
            float ev[8] = {e0.x, e0.y, e0.z, e0.w, e1.x, e1.y, e1.z, e1.w};
            #pragma unroll
            for (int j = 0; j < 8; ++j)
                #pragma unroll
                for (int i = 0; i < 8; ++i)
                    acc[j][i] += hv[j] * ev[i];
        }
        __syncthreads();
    }
    // epilogue: round to bf16, per-row partial max/expsum (16 tx lanes own one
    // row's 128 v), pack+store 8 bf16 per row as uint4.
    #pragma unroll
    for (int j = 0; j < 8; ++j) {
        int bt = 8 * ty + j;
        unsigned bb[8];
        float r[8];
        float m = -1e30f;
        #pragma unroll
        for (int i = 0; i < 8; ++i) {
            bb[i] = bf16rne(acc[j][i]);
            r[i] = __uint_as_float(bb[i] << 16);
            m = fmaxf(m, r[i]);
        }
        #pragma unroll
        for (int o = 8; o >= 1; o >>= 1) m = fmaxf(m, __shfl_xor(m, o, 16));
        float es = 0.0f;
        #pragma unroll
        for (int i = 0; i < 8; ++i) es += __expf(r[i] - m);
        #pragma unroll
        for (int o = 8; o >= 1; o >>= 1) es += __shfl_xor(es, o, 16);
        if (tx == 0) {
            pmax[bid * BTq + bt] = m;
            psum[bid * BTq + bt] = es;
        }
        uint4 w = make_uint4(bb[0] | (bb[1] << 16), bb[2] | (bb[3] << 16),
                             bb[4] | (bb[5] << 16), bb[6] | (bb[7] << 16));
        *(uint4*)(logits + (size_t)bt * Vq + v0 + 8 * tx) = w;
    }
}

// single streaming pass: finalize (m,s) from 250 partials, then
// out = pg*softmax(logits) + (1-pg)*pctx over a 4000-v chunk. 1024 blocks.
__global__ __launch_bounds__(256) void k_final(const unsigned short* __restrict__ logits,
                                               const float* __restrict__ pctx,
                                               const float* __restrict__ pgen,
                                               const float* __restrict__ pmax,
                                               const float* __restrict__ psum,
                                               float* __restrict__ out) {
    __shared__ float red[4];
    int bid = blockIdx.x, tid = threadIdx.x;
    int bt = bid >> 3, ch = bid & 7;
    float pm = (tid < NCOMPUTE) ? pmax[tid * BTq + bt] : -1e30f;
    float m = blockReduceMax(pm, red);
    float part = (tid < NCOMPUTE) ? psum[tid * BTq + bt] * __expf(pm - m) : 0.0f;
    float s = blockReduceSum(part, red);
    float inv = 1.0f / s, pg = pgen[bt], cg = 1.0f - pg;
    size_t rowoff = (size_t)bt * Vq + (size_t)ch * FCH;
    const uint4*  l4 = (const uint4*)(logits + rowoff);   // 500 uint4 (8 bf16 each)
    const float4* p4 = (const float4*)(pctx + rowoff);
    float4*       o4 = (float4*)(out + rowoff);
    for (int i = tid; i < FCH / 8; i += 256) {
        uint4 lv = l4[i];
        float4 pa = p4[2 * i], pb = p4[2 * i + 1];
        float f0 = __uint_as_float(lv.x << 16), f1 = __uint_as_float(lv.x & 0xFFFF0000u);
        float f2 = __uint_as_float(lv.y << 16), f3 = __uint_as_float(lv.y & 0xFFFF0000u);
        float f4 = __uint_as_float(lv.z << 16), f5 = __uint_as_float(lv.z & 0xFFFF0000u);
        float f6 = __uint_as_float(lv.w << 16), f7 = __uint_as_float(lv.w & 0xFFFF0000u);
        float4 oa = make_float4(pg * __expf(f0 - m) * inv + cg * pa.x,
                                pg * __expf(f1 - m) * inv + cg * pa.y,
                                pg * __expf(f2 - m) * inv + cg * pa.z,
                                pg * __expf(f3 - m) * inv + cg * pa.w);
        float4 ob = make_float4(pg * __expf(f4 - m) * inv + cg * pb.x,
                                pg * __expf(f5 - m) * inv + cg * pb.y,
                                pg * __expf(f6 - m) * inv + cg * pb.z,
                                pg * __expf(f7 - m) * inv + cg * pb.w);
        o4[2 * i]     = oa;
        o4[2 * i + 1] = ob;
    }
}

extern "C" void kernel_launch(void* const* d_in, const int* in_sizes, int n_in,
                              void* d_out, int out_size, void* d_ws, size_t ws_size,
                              hipStream_t stream) {
    const float* enc_hidden = (const float*)d_in[0];
    const float* enc_out    = (const float*)d_in[1];
    const int*   story      = (const int*)d_in[2];
    const int*   trg        = (const int*)d_in[3];
    const float* shared_emb = (const float*)d_in[4];
    const float* slot_emb   = (const float*)d_in[5];
    const float* w_ih       = (const float*)d_in[6];
    const float* w_hh       = (const float*)d_in[7];
    const float* b_ih       = (const float*)d_in[8];
    const float* b_hh       = (const float*)d_in[9];
    const float* w_ratio_w  = (const float*)d_in[10];
    const float* w_ratio_b  = (const float*)d_in[11];
    const float* w_gate_w   = (const float*)d_in[12];
    const float* w_gate_b   = (const float*)d_in[13];

    float* out = (float*)d_out;

    // All scratch in d_ws.
    float* ws = (float*)d_ws;
    unsigned short* logits_buf = (unsigned short*)ws;   // 4,096,000 bf16 (8.2 MB, in first SLICE region)
    float* pctx_buf   = ws + (size_t)SLICE;        // 4,096,000 f
    float* gi_buf     = ws + 2 * (size_t)SLICE;    // 153,600 f
    float* gh_buf     = gi_buf + 153600;           // 19,200 f
    float* hT_buf     = gh_buf + 19200;            // 51,200 f
    float* pgen_buf   = hT_buf + 51200;            // 128 f
    float* pmax_buf   = pgen_buf + 128;            // 32,000 f (250 x 128)
    float* psum_buf   = pmax_buf + 32000;          // 32,000 f

    hipLaunchKernelGGL(k_gates, dim3(GCOMPUTE + PCTX_ZB), dim3(256), 0, stream,
                       enc_hidden, shared_emb, slot_emb, w_ih, w_hh, b_ih, b_hh, trg,
                       gi_buf, gh_buf, pctx_buf);
    hipLaunchKernelGGL(k_attn, dim3(BTq), dim3(512), 0, stream,
                       gi_buf, gh_buf, enc_hidden, shared_emb, slot_emb, trg,
                       enc_out, story, w_ratio_w, w_ratio_b, w_gate_w, w_gate_b,
                       pctx_buf, pgen_buf, hT_buf, out + PTR_TOTAL);
    hipLaunchKernelGGL(k_logits, dim3(NCOMPUTE + NZERO + 1), dim3(256), 0, stream,
                       hT_buf, shared_emb, logits_buf, pmax_buf, psum_buf, out);
    hipLaunchKernelGGL(k_final, dim3(BTq * FBLK), dim3(256), 0, stream,
                       logits_buf, pctx_buf, pgen_buf, pmax_buf, psum_buf, out);
}

// Round 3
// 742.601 us; speedup vs baseline: 1.0334x; 1.0109x over previous
//
#include <hip/hip_runtime.h>

#define Bq 16
#define Sq 512
#define Dq 400
#define Vq 32000
#define Tq 8
#define NSq 30
#define NGq 3
#define BTq (Bq*Tq)                     // 128
#define SLICE 4096000                   // Bq*Tq*Vq, one ptr slice (elems)
#define PTR_TOTAL (30ull*SLICE)         // 122,880,000
#define GATE_TOTAL (NSq*Bq*NGq)         // 1440

// zero-fill of out ptr slices 1..29: 29*SLICE/4 = 29,696,000 float4 total,
// split across the three leading kernels to fill their idle HBM BW.
#define ZTOT 29696000ull                // float4 count
#define ZPER 16384                      // float4 per zero block
#define GZB 256                         // zero blocks in k_gates   (67.1 MB)
#define AZB 384                         // zero blocks in k_attn    (100.7 MB)
#define LZB 1173                        // zero blocks in k_logits  (307.3 MB)
// GZB+AZB+LZB = 1813; 1813*16384 = 29,704,192 (last block bounds-guarded)

#define NCOMPUTE 250                    // k_logits GEMM blocks
#define GCOMPUTE 64                     // k_gates GEMM blocks

// k_final: 8 blocks per bt row, single streaming pass
#define FBLK 8
#define FCH (Vq/FBLK)                   // 4000 v per block

__device__ inline float sigmoidf_(float x) { return 1.0f / (1.0f + __expf(-x)); }

// round-to-nearest-even f32 -> bf16 (as ushort in low 16 bits)
__device__ inline unsigned bf16rne(float x) {
    unsigned u = __float_as_uint(x);
    return (u + 0x7FFFu + ((u >> 16) & 1u)) >> 16;
}

__device__ inline float blockReduceSum(float v, float* red) {
    int tid = threadIdx.x;
    #pragma unroll
    for (int o = 32; o > 0; o >>= 1) v += __shfl_down(v, o, 64);
    if ((tid & 63) == 0) red[tid >> 6] = v;
    __syncthreads();
    if (tid == 0) {
        float s = red[0];
        int nw = blockDim.x >> 6;
        for (int i = 1; i < nw; i++) s += red[i];
        red[0] = s;
    }
    __syncthreads();
    float r = red[0];
    __syncthreads();
    return r;
}

__device__ inline float blockReduceMax(float v, float* red) {
    int tid = threadIdx.x;
    #pragma unroll
    for (int o = 32; o > 0; o >>= 1) v = fmaxf(v, __shfl_down(v, o, 64));
    if ((tid & 63) == 0) red[tid >> 6] = v;
    __syncthreads();
    if (tid == 0) {
        float s = red[0];
        int nw = blockDim.x >> 6;
        for (int i = 1; i < nw; i++) s = fmaxf(s, red[i]);
        red[0] = s;
    }
    __syncthreads();
    float r = red[0];
    __syncthreads();
    return r;
}

// gi = X @ w_ih^T + b_ih (128x1200), gh = h0 @ w_hh^T + b_hh (16x1200).
// blocks [0,64) = 16 b x 4 j-tiles(300). A rows 0..7 = x(t), row 8 = h0.
// blocks [64,64+GZB) zero the first 67 MB of out ptr slices 1..29.
__global__ __launch_bounds__(256) void k_gates(const float* __restrict__ enc_hidden,
                                               const float* __restrict__ shared_emb,
                                               const float* __restrict__ slot_emb,
                                               const float* __restrict__ w_ih,
                                               const float* __restrict__ w_hh,
                                               const float* __restrict__ b_ih,
                                               const float* __restrict__ b_hh,
                                               const int* __restrict__ trg,
                                               float* __restrict__ gi, float* __restrict__ gh,
                                               float* __restrict__ out) {
    int tid = threadIdx.x;
    if (blockIdx.x >= GCOMPUTE) {
        int zb = blockIdx.x - GCOMPUTE;               // [0,GZB)
        float4 z = make_float4(0.0f, 0.0f, 0.0f, 0.0f);
        float4* dst = (float4*)(out + (size_t)SLICE);
        size_t base = (size_t)zb * ZPER + tid;
        #pragma unroll
        for (int r = 0; r < ZPER / 256; ++r) {
            size_t idx = base + (size_t)r * 256;
            if (idx < ZTOT) dst[idx] = z;
        }
        return;
    }
    __shared__ float A[9][Dq];
    __shared__ int toks[8];
    int b = blockIdx.x >> 2, jt = blockIdx.x & 3;
    if (tid < 7) toks[tid + 1] = trg[b * (NSq * Tq) + tid];
    __syncthreads();
    for (int idx = tid; idx < 900; idx += 256) {      // 9 rows x 100 float4
        int r = idx / 100, q = idx - r * 100;
        const float4* src;
        if (r == 8)      src = (const float4*)(enc_hidden + b * Dq);
        else if (r == 0) src = (const float4*)slot_emb;
        else             src = (const float4*)(shared_emb + (size_t)toks[r] * Dq);
        *(float4*)&A[r][4 * q] = src[q];
    }
    __syncthreads();
    for (int o = tid; o < 2700; o += 256) {           // 9 rows x 300 j
        int r = o / 300, jj = o - r * 300;
        int j = jt * 300 + jj;
        const float* w = (r == 8) ? w_hh : w_ih;
        const float4* w4 = (const float4*)(w + (size_t)j * Dq);
        const float4* a4 = (const float4*)&A[r][0];
        float acc = (r == 8) ? b_hh[j] : b_ih[j];
        #pragma unroll 4
        for (int q = 0; q < Dq / 4; ++q) {
            float4 wv = w4[q], av = a4[q];
            acc += av.x * wv.x + av.y * wv.y + av.z * wv.z + av.w * wv.w;
        }
        if (r == 8) gh[b * 1200 + j] = acc;
        else        gi[(b * 8 + r) * 1200 + j] = acc;
    }
}

// blocks [0,128): GRU elementwise + scores + softmax -> probs_buf + context(RAW
// scores) + p_gen + gate0 + hT write. blocks [128,128+AZB): zero-fill 101 MB of
// out ptr slices (overlaps attn compute with spare HBM BW).
__global__ __launch_bounds__(512) void k_attn(const float* __restrict__ gi,
                                              const float* __restrict__ gh,
                                              const float* __restrict__ enc_hidden,
                                              const float* __restrict__ shared_emb,
                                              const float* __restrict__ slot_emb,
                                              const int* __restrict__ trg,
                                              const float* __restrict__ enc_out,
                                              const int* __restrict__ story,
                                              const float* __restrict__ w_ratio_w,
                                              const float* __restrict__ w_ratio_b,
                                              const float* __restrict__ w_gate_w,
                                              const float* __restrict__ w_gate_b,
                                              float* __restrict__ probs, float* __restrict__ pgen,
                                              float* __restrict__ hT, float* __restrict__ out_gate,
                                              float* __restrict__ out) {
    int tid = threadIdx.x;
    if (blockIdx.x >= BTq) {
        int zb = GZB + (blockIdx.x - BTq);            // global zero idx [GZB,GZB+AZB)
        float4 z = make_float4(0.0f, 0.0f, 0.0f, 0.0f);
        float4* dst = (float4*)(out + (size_t)SLICE);
        size_t base = (size_t)zb * ZPER + tid;
        #pragma unroll
        for (int r = 0; r < ZPER / 512; ++r) {
            size_t idx = base + (size_t)r * 512;
            if (idx < ZTOT) dst[idx] = z;
        }
        return;
    }
    __shared__ float h_l[Dq], ctx_l[Dq], x_l[Dq], sc_l[Sq], red[8];
    int bt = blockIdx.x, b = bt >> 3, t = bt & 7;
    if (tid < Dq) {
        int d = tid;
        float x = (t == 0) ? slot_emb[d]
                           : shared_emb[(size_t)trg[b * (NSq * Tq) + (t - 1)] * Dq + d];
        float h0 = enc_hidden[b * Dq + d];
        const float* gib = gi + bt * 1200;
        const float* ghb = gh + b * 1200;
        float r_ = sigmoidf_(gib[d] + ghb[d]);
        float z  = sigmoidf_(gib[Dq + d] + ghb[Dq + d]);
        float n  = tanhf(gib[2 * Dq + d] + r_ * ghb[2 * Dq + d]);
        float h  = (1.0f - z) * n + z * h0;
        h_l[d] = h; x_l[d] = x;
        hT[d * BTq + bt] = h;
    }
    __syncthreads();
    {   // scores: one s per thread
        const float4* e4 = (const float4*)(enc_out + ((size_t)(b * Sq + tid)) * Dq);
        float acc = 0.0f;
        for (int q = 0; q < Dq / 4; ++q) {
            float4 p = e4[q];
            int k = 4 * q;
            acc += h_l[k]*p.x + h_l[k+1]*p.y + h_l[k+2]*p.z + h_l[k+3]*p.w;
        }
        sc_l[tid] = acc;
    }
    __syncthreads();
    float myv = sc_l[tid];
    float m = blockReduceMax(myv, red);
    float e = __expf(myv - m);
    float ssum = blockReduceSum(e, red);
    probs[bt * Sq + tid] = e / ssum;                  // scatter deferred to k_final (LDS)
    // context from RAW scores
    for (int d = tid; d < Dq; d += 512) {
        float acc = 0.0f;
        #pragma unroll 8
        for (int s = 0; s < Sq; ++s)
            acc += sc_l[s] * enc_out[((size_t)(b * Sq + s)) * Dq + d];
        ctx_l[d] = acc;
    }
    __syncthreads();
    {   // p_gen = sigmoid([h,ctx,X] . w_ratio + b)
        float part = 0.0f;
        for (int i = tid; i < 1200; i += 512) {
            float v = (i < Dq) ? h_l[i] : (i < 2 * Dq ? ctx_l[i - Dq] : x_l[i - 2 * Dq]);
            part += v * w_ratio_w[i];
        }
        float tot = blockReduceSum(part, red);
        if (tid == 0) pgen[bt] = sigmoidf_(tot + w_ratio_b[0]);
    }
    if (t == 0) {
        for (int g = 0; g < NGq; ++g) {
            float part = 0.0f;
            for (int d = tid; d < Dq; d += 512) part += ctx_l[d] * w_gate_w[g * Dq + d];
            float tot = blockReduceSum(part, red);
            if (tid == 0) out_gate[b * NGq + g] = tot + w_gate_b[g];
        }
    }
}

// Fused: [0,250) logits GEMM blocks (bf16 logits + per-block softmax partials);
// [250,250+LZB) zero-fill remaining out ptr slices; last block zeroes gate
// slices 1..29.
#define TVL 128
#define CKL 40
__global__ __launch_bounds__(256) void k_logits(const float* __restrict__ hT,
                                                const float* __restrict__ emb,
                                                unsigned short* __restrict__ logits,
                                                float* __restrict__ pmax,
                                                float* __restrict__ psum,
                                                float* __restrict__ out) {
    __shared__ float eT[CKL][132];
    __shared__ float hL[CKL][132];
    int bid = blockIdx.x;
    int tid = threadIdx.x;
    if (bid >= NCOMPUTE) {
        int zl = bid - NCOMPUTE;
        float4 z = make_float4(0.0f, 0.0f, 0.0f, 0.0f);
        if (zl < LZB) {
            int zb = GZB + AZB + zl;                  // global zero idx
            float4* dst = (float4*)(out + (size_t)SLICE);
            size_t base = (size_t)zb * ZPER + tid;
            #pragma unroll
            for (int r = 0; r < ZPER / 256; ++r) {
                size_t idx = base + (size_t)r * 256;
                if (idx < ZTOT) dst[idx] = z;
            }
        } else {
            float4* g = (float4*)(out + PTR_TOTAL + Bq * NGq);
            for (int i = tid; i < (GATE_TOTAL - Bq * NGq) / 4; i += 256) g[i] = z;
        }
        return;
    }
    int v0 = bid * TVL;
    int tx = tid & 15, ty = tid >> 4;
    float acc[8][8];
    #pragma unroll
    for (int j = 0; j < 8; ++j)
        #pragma unroll
        for (int i = 0; i < 8; ++i) acc[j][i] = 0.0f;

    for (int c = 0; c < Dq / CKL; ++c) {
        int k0 = c * CKL;
        const float4* hg = (const float4*)(hT + (size_t)k0 * BTq);
        #pragma unroll
        for (int r = 0; r < 5; ++r) {
            int idx = tid + 256 * r;
            int k = idx >> 5, c4 = idx & 31;
            float4 vd = hg[idx];
            *(float4*)&hL[k][4 * c4] = vd;
        }
        #pragma unroll
        for (int r = 0; r < 5; ++r) {
            int idx = tid + 256 * r;
            int v = idx / 10, q = idx - 10 * v;
            float4 vd = *(const float4*)(emb + (size_t)(v0 + v) * Dq + k0 + 4 * q);
            eT[4*q+0][v] = vd.x; eT[4*q+1][v] = vd.y; eT[4*q+2][v] = vd.z; eT[4*q+3][v] = vd.w;
        }
        __syncthreads();
        #pragma unroll 4
        for (int k = 0; k < CKL; ++k) {
            float4 h0 = *(const float4*)&hL[k][8 * ty];
            float4 h1 = *(const float4*)&hL[k][8 * ty + 4];
            float4 e0 = *(const float4*)&eT[k][8 * tx];
            float4 e1 = *(const float4*)&eT[k][8 * tx + 4];
            float hv[8] = {h0.x, h0.y, h0.z, h0.w, h1.x, h1.y, h1.z, h1.w};
            float ev[8] = {e0.x, e0.y, e0.z, e0.w, e1.x, e1.y, e1.z, e1.w};
            #pragma unroll
            for (int j = 0; j < 8; ++j)
                #pragma unroll
                for (int i = 0; i < 8; ++i)
                    acc[j][i] += hv[j] * ev[i];
        }
        __syncthreads();
    }
    // epilogue: round to bf16, per-row partial max/expsum (16 tx lanes own one
    // row's 128 v), pack+store 8 bf16 per row as uint4.
    #pragma unroll
    for (int j = 0; j < 8; ++j) {
        int bt = 8 * ty + j;
        unsigned bb[8];
        float r[8];
        float m = -1e30f;
        #pragma unroll
        for (int i = 0; i < 8; ++i) {
            bb[i] = bf16rne(acc[j][i]);
            r[i] = __uint_as_float(bb[i] << 16);
            m = fmaxf(m, r[i]);
        }
        #pragma unroll
        for (int o = 8; o >= 1; o >>= 1) m = fmaxf(m, __shfl_xor(m, o, 16));
        float es = 0.0f;
        #pragma unroll
        for (int i = 0; i < 8; ++i) es += __expf(r[i] - m);
        #pragma unroll
        for (int o = 8; o >= 1; o >>= 1) es += __shfl_xor(es, o, 16);
        if (tx == 0) {
            pmax[bid * BTq + bt] = m;
            psum[bid * BTq + bt] = es;
        }
        uint4 w = make_uint4(bb[0] | (bb[1] << 16), bb[2] | (bb[3] << 16),
                             bb[4] | (bb[5] << 16), bb[6] | (bb[7] << 16));
        *(uint4*)(logits + (size_t)bt * Vq + v0 + 8 * tx) = w;
    }
}

// single streaming pass: finalize (m,s) from 250 partials; build the 4000-v
// chunk in LDS (pg*softmax), scatter-add (1-pg)*probs via story tokens (LDS
// atomics handle duplicates), then one coalesced write. 1024 blocks.
__global__ __launch_bounds__(256) void k_final(const unsigned short* __restrict__ logits,
                                               const float* __restrict__ probs,
                                               const int* __restrict__ story,
                                               const float* __restrict__ pgen,
                                               const float* __restrict__ pmax,
                                               const float* __restrict__ psum,
                                               float* __restrict__ out) {
    __shared__ float chunk[FCH];                      // 16 KB
    __shared__ float red[4];
    int bid = blockIdx.x, tid = threadIdx.x;
    int bt = bid >> 3, ch = bid & 7, b = bt >> 3;
    float pm = (tid < NCOMPUTE) ? pmax[tid * BTq + bt] : -1e30f;
    float m = blockReduceMax(pm, red);
    float part = (tid < NCOMPUTE) ? psum[tid * BTq + bt] * __expf(pm - m) : 0.0f;
    float s = blockReduceSum(part, red);
    float inv = 1.0f / s, pg = pgen[bt], cg = 1.0f - pg;
    int lo = ch * FCH;
    const uint4* l4 = (const uint4*)(logits + (size_t)bt * Vq + lo);  // 500 uint4
    for (int i = tid; i < FCH / 8; i += 256) {
        uint4 lv = l4[i];
        float f0 = __uint_as_float(lv.x << 16), f1 = __uint_as_float(lv.x & 0xFFFF0000u);
        float f2 = __uint_as_float(lv.y << 16), f3 = __uint_as_float(lv.y & 0xFFFF0000u);
        float f4 = __uint_as_float(lv.z << 16), f5 = __uint_as_float(lv.z & 0xFFFF0000u);
        float f6 = __uint_as_float(lv.w << 16), f7 = __uint_as_float(lv.w & 0xFFFF0000u);
        chunk[8 * i + 0] = pg * __expf(f0 - m) * inv;
        chunk[8 * i + 1] = pg * __expf(f1 - m) * inv;
        chunk[8 * i + 2] = pg * __expf(f2 - m) * inv;
        chunk[8 * i + 3] = pg * __expf(f3 - m) * inv;
        chunk[8 * i + 4] = pg * __expf(f4 - m) * inv;
        chunk[8 * i + 5] = pg * __expf(f5 - m) * inv;
        chunk[8 * i + 6] = pg * __expf(f6 - m) * inv;
        chunk[8 * i + 7] = pg * __expf(f7 - m) * inv;
    }
    __syncthreads();
    for (int ss = tid; ss < Sq; ss += 256) {
        int rel = story[b * Sq + ss] - lo;
        if (rel >= 0 && rel < FCH)
            atomicAdd(&chunk[rel], cg * probs[bt * Sq + ss]);
    }
    __syncthreads();
    float4* o4 = (float4*)(out + (size_t)bt * Vq + lo);
    const float4* c4 = (const float4*)chunk;
    for (int i = tid; i < FCH / 4; i += 256) o4[i] = c4[i];
}

extern "C" void kernel_launch(void* const* d_in, const int* in_sizes, int n_in,
                              void* d_out, int out_size, void* d_ws, size_t ws_size,
                              hipStream_t stream) {
    const float* enc_hidden = (const float*)d_in[0];
    const float* enc_out    = (const float*)d_in[1];
    const int*   story      = (const int*)d_in[2];
    const int*   trg        = (const int*)d_in[3];
    const float* shared_emb = (const float*)d_in[4];
    const float* slot_emb   = (const float*)d_in[5];
    const float* w_ih       = (const float*)d_in[6];
    const float* w_hh       = (const float*)d_in[7];
    const float* b_ih       = (const float*)d_in[8];
    const float* b_hh       = (const float*)d_in[9];
    const float* w_ratio_w  = (const float*)d_in[10];
    const float* w_ratio_b  = (const float*)d_in[11];
    const float* w_gate_w   = (const float*)d_in[12];
    const float* w_gate_b   = (const float*)d_in[13];

    float* out = (float*)d_out;

    // All scratch in d_ws.
    float* ws = (float*)d_ws;
    unsigned short* logits_buf = (unsigned short*)ws;  // 4,096,000 bf16 (8.2 MB)
    float* probs_buf  = ws + (size_t)SLICE;        // 65,536 f (128 x 512)
    float* gi_buf     = ws + 2 * (size_t)SLICE;    // 153,600 f
    float* gh_buf     = gi_buf + 153600;           // 19,200 f
    float* hT_buf     = gh_buf + 19200;            // 51,200 f
    float* pgen_buf   = hT_buf + 51200;            // 128 f
    float* pmax_buf   = pgen_buf + 128;            // 32,000 f (250 x 128)
    float* psum_buf   = pmax_buf + 32000;          // 32,000 f

    hipLaunchKernelGGL(k_gates, dim3(GCOMPUTE + GZB), dim3(256), 0, stream,
                       enc_hidden, shared_emb, slot_emb, w_ih, w_hh, b_ih, b_hh, trg,
                       gi_buf, gh_buf, out);
    hipLaunchKernelGGL(k_attn, dim3(BTq + AZB), dim3(512), 0, stream,
                       gi_buf, gh_buf, enc_hidden, shared_emb, slot_emb, trg,
                       enc_out, story, w_ratio_w, w_ratio_b, w_gate_w, w_gate_b,
                       probs_buf, pgen_buf, hT_buf, out + PTR_TOTAL, out);
    hipLaunchKernelGGL(k_logits, dim3(NCOMPUTE + LZB + 1), dim3(256), 0, stream,
                       hT_buf, shared_emb, logits_buf, pmax_buf, psum_buf, out);
    hipLaunchKernelGGL(k_final, dim3(BTq * FBLK), dim3(256), 0, stream,
                       logits_buf, probs_buf, story, pgen_buf, pmax_buf, psum_buf, out);
}

// Round 5
// 735.675 us; speedup vs baseline: 1.0431x; 1.0094x over previous
//
#include <hip/hip_runtime.h>

#define Bq 16
#define Sq 512
#define Dq 400
#define Vq 32000
#define Tq 8
#define NSq 30
#define NGq 3
#define BTq (Bq*Tq)                     // 128
#define SLICE 4096000                   // Bq*Tq*Vq, one ptr slice (elems)
#define PTR_TOTAL (30ull*SLICE)         // 122,880,000
#define GATE_TOTAL (NSq*Bq*NGq)         // 1440

// zero-fill of out ptr slices 1..29: 29*SLICE/4 = 29,696,000 float4 total,
// split across k_attn and k_logits to fill their idle HBM BW.
#define ZTOT 29696000ull                // float4 count
#define ZPER 16384                      // float4 per zero block
#define AZB 640                         // zero blocks in k_attn    (167.8 MB)
#define LZB 1173                        // zero blocks in k_logits  (307.3 MB)
// AZB+LZB = 1813; 1813*16384 = 29,704,192 (last block bounds-guarded)

#define NCOMPUTE 250                    // k_logits GEMM blocks

// k_final: 8 blocks per bt row, single streaming pass
#define FBLK 8
#define FCH (Vq/FBLK)                   // 4000 v per block

// native clang vector for nontemporal 16B stores (HIP float4 is a struct the
// builtin rejects)
typedef float f4nt __attribute__((ext_vector_type(4)));

__device__ inline float sigmoidf_(float x) { return 1.0f / (1.0f + __expf(-x)); }

// round-to-nearest-even f32 -> bf16 (as ushort in low 16 bits)
__device__ inline unsigned bf16rne(float x) {
    unsigned u = __float_as_uint(x);
    return (u + 0x7FFFu + ((u >> 16) & 1u)) >> 16;
}

__device__ inline float blockReduceSum(float v, float* red) {
    int tid = threadIdx.x;
    #pragma unroll
    for (int o = 32; o > 0; o >>= 1) v += __shfl_down(v, o, 64);
    if ((tid & 63) == 0) red[tid >> 6] = v;
    __syncthreads();
    if (tid == 0) {
        float s = red[0];
        int nw = blockDim.x >> 6;
        for (int i = 1; i < nw; i++) s += red[i];
        red[0] = s;
    }
    __syncthreads();
    float r = red[0];
    __syncthreads();
    return r;
}

__device__ inline float blockReduceMax(float v, float* red) {
    int tid = threadIdx.x;
    #pragma unroll
    for (int o = 32; o > 0; o >>= 1) v = fmaxf(v, __shfl_down(v, o, 64));
    if ((tid & 63) == 0) red[tid >> 6] = v;
    __syncthreads();
    if (tid == 0) {
        float s = red[0];
        int nw = blockDim.x >> 6;
        for (int i = 1; i < nw; i++) s = fmaxf(s, red[i]);
        red[0] = s;
    }
    __syncthreads();
    float r = red[0];
    __syncthreads();
    return r;
}

// blocks [0,128): per-(b,t) fused GRU gates (recomputed from w_ih/w_hh via L2)
// + elementwise + scores + softmax -> probs_buf + context(RAW scores) + p_gen
// + gate0 + hT write. blocks [128,128+AZB): nontemporal zero-fill 168 MB of
// out ptr slices (overlaps gate/attn compute with spare HBM BW).
__global__ __launch_bounds__(512) void k_attn(const float* __restrict__ enc_hidden,
                                              const float* __restrict__ shared_emb,
                                              const float* __restrict__ slot_emb,
                                              const float* __restrict__ w_ih,
                                              const float* __restrict__ w_hh,
                                              const float* __restrict__ b_ih,
                                              const float* __restrict__ b_hh,
                                              const int* __restrict__ trg,
                                              const float* __restrict__ enc_out,
                                              const int* __restrict__ story,
                                              const float* __restrict__ w_ratio_w,
                                              const float* __restrict__ w_ratio_b,
                                              const float* __restrict__ w_gate_w,
                                              const float* __restrict__ w_gate_b,
                                              float* __restrict__ probs, float* __restrict__ pgen,
                                              float* __restrict__ hT, float* __restrict__ out_gate,
                                              float* __restrict__ out) {
    int tid = threadIdx.x;
    if (blockIdx.x >= BTq) {
        int zb = blockIdx.x - BTq;                    // global zero idx [0,AZB)
        f4nt z = (f4nt)(0.0f);
        f4nt* dst = (f4nt*)(out + (size_t)SLICE);
        size_t base = (size_t)zb * ZPER + tid;
        #pragma unroll
        for (int r = 0; r < ZPER / 512; ++r) {
            size_t idx = base + (size_t)r * 512;
            if (idx < ZTOT) __builtin_nontemporal_store(z, &dst[idx]);
        }
        return;
    }
    __shared__ float x_l[Dq], h0_l[Dq], h_l[Dq], ctx_l[Dq], sc_l[Sq];
    __shared__ float gi_l[1200], gh_l[1200];
    __shared__ float red[8];
    int bt = blockIdx.x, b = bt >> 3, t = bt & 7;
    if (tid < 100) {
        const float4* src = (t == 0) ? (const float4*)slot_emb
            : (const float4*)(shared_emb + (size_t)trg[b * (NSq * Tq) + (t - 1)] * Dq);
        *(float4*)&x_l[4 * tid] = src[tid];
    } else if (tid >= 256 && tid < 356) {
        int q = tid - 256;
        *(float4*)&h0_l[4 * q] = ((const float4*)(enc_hidden + b * Dq))[q];
    }
    __syncthreads();
    // gates: each thread computes gi[j] and gh[j] for j = tid, tid+512, tid+1024
    for (int j = tid; j < 1200; j += 512) {
        const float4* wi4 = (const float4*)(w_ih + (size_t)j * Dq);
        const float4* wh4 = (const float4*)(w_hh + (size_t)j * Dq);
        const float4* x4  = (const float4*)x_l;
        const float4* h4  = (const float4*)h0_l;
        float ai = b_ih[j], ah = b_hh[j];
        #pragma unroll 4
        for (int q = 0; q < Dq / 4; ++q) {
            float4 wv = wi4[q], av = x4[q];
            ai += av.x * wv.x + av.y * wv.y + av.z * wv.z + av.w * wv.w;
            float4 wh = wh4[q], hv = h4[q];
            ah += hv.x * wh.x + hv.y * wh.y + hv.z * wh.z + hv.w * wh.w;
        }
        gi_l[j] = ai; gh_l[j] = ah;
    }
    __syncthreads();
    if (tid < Dq) {
        int d = tid;
        float r_ = sigmoidf_(gi_l[d] + gh_l[d]);
        float z  = sigmoidf_(gi_l[Dq + d] + gh_l[Dq + d]);
        float n  = tanhf(gi_l[2 * Dq + d] + r_ * gh_l[2 * Dq + d]);
        float h  = (1.0f - z) * n + z * h0_l[d];
        h_l[d] = h;
        hT[d * BTq + bt] = h;
    }
    __syncthreads();
    {   // scores: one s per thread
        const float4* e4 = (const float4*)(enc_out + ((size_t)(b * Sq + tid)) * Dq);
        float acc = 0.0f;
        for (int q = 0; q < Dq / 4; ++q) {
            float4 p = e4[q];
            int k = 4 * q;
            acc += h_l[k]*p.x + h_l[k+1]*p.y + h_l[k+2]*p.z + h_l[k+3]*p.w;
        }
        sc_l[tid] = acc;
    }
    __syncthreads();
    float myv = sc_l[tid];
    float m = blockReduceMax(myv, red);
    float e = __expf(myv - m);
    float ssum = blockReduceSum(e, red);
    probs[bt * Sq + tid] = e / ssum;                  // scatter deferred to k_final (LDS)
    // context from RAW scores
    for (int d = tid; d < Dq; d += 512) {
        float acc = 0.0f;
        #pragma unroll 8
        for (int s = 0; s < Sq; ++s)
            acc += sc_l[s] * enc_out[((size_t)(b * Sq + s)) * Dq + d];
        ctx_l[d] = acc;
    }
    __syncthreads();
    {   // p_gen = sigmoid([h,ctx,X] . w_ratio + b)
        float part = 0.0f;
        for (int i = tid; i < 1200; i += 512) {
            float v = (i < Dq) ? h_l[i] : (i < 2 * Dq ? ctx_l[i - Dq] : x_l[i - 2 * Dq]);
            part += v * w_ratio_w[i];
        }
        float tot = blockReduceSum(part, red);
        if (tid == 0) pgen[bt] = sigmoidf_(tot + w_ratio_b[0]);
    }
    if (t == 0) {
        for (int g = 0; g < NGq; ++g) {
            float part = 0.0f;
            for (int d = tid; d < Dq; d += 512) part += ctx_l[d] * w_gate_w[g * Dq + d];
            float tot = blockReduceSum(part, red);
            if (tid == 0) out_gate[b * NGq + g] = tot + w_gate_b[g];
        }
    }
}

// Fused: [0,250) logits GEMM blocks (bf16 logits + per-block softmax partials);
// [250,250+LZB) nontemporal zero-fill remaining out ptr slices; last block
// zeroes gate slices 1..29.
#define TVL 128
#define CKL 40
__global__ __launch_bounds__(256) void k_logits(const float* __restrict__ hT,
                                                const float* __restrict__ emb,
                                                unsigned short* __restrict__ logits,
                                                float* __restrict__ pmax,
                                                float* __restrict__ psum,
                                                float* __restrict__ out) {
    __shared__ float eT[CKL][132];
    __shared__ float hL[CKL][132];
    int bid = blockIdx.x;
    int tid = threadIdx.x;
    if (bid >= NCOMPUTE) {
        int zl = bid - NCOMPUTE;
        if (zl < LZB) {
            int zb = AZB + zl;                        // global zero idx
            f4nt z = (f4nt)(0.0f);
            f4nt* dst = (f4nt*)(out + (size_t)SLICE);
            size_t base = (size_t)zb * ZPER + tid;
            #pragma unroll
            for (int r = 0; r < ZPER / 256; ++r) {
                size_t idx = base + (size_t)r * 256;
                if (idx < ZTOT) __builtin_nontemporal_store(z, &dst[idx]);
            }
        } else {
            float4 z4 = make_float4(0.0f, 0.0f, 0.0f, 0.0f);
            float4* g = (float4*)(out + PTR_TOTAL + Bq * NGq);
            for (int i = tid; i < (GATE_TOTAL - Bq * NGq) / 4; i += 256) g[i] = z4;
        }
        return;
    }
    int v0 = bid * TVL;
    int tx = tid & 15, ty = tid >> 4;
    float acc[8][8];
    #pragma unroll
    for (int j = 0; j < 8; ++j)
        #pragma unroll
        for (int i = 0; i < 8; ++i) acc[j][i] = 0.0f;

    for (int c = 0; c < Dq / CKL; ++c) {
        int k0 = c * CKL;
        const float4* hg = (const float4*)(hT + (size_t)k0 * BTq);
        #pragma unroll
        for (int r = 0; r < 5; ++r) {
            int idx = tid + 256 * r;
            int k = idx >> 5, c4 = idx & 31;
            float4 vd = hg[idx];
            *(float4*)&hL[k][4 * c4] = vd;
        }
        #pragma unroll
        for (int r = 0; r < 5; ++r) {
            int idx = tid + 256 * r;
            int v = idx / 10, q = idx - 10 * v;
            float4 vd = *(const float4*)(emb + (size_t)(v0 + v) * Dq + k0 + 4 * q);
            eT[4*q+0][v] = vd.x; eT[4*q+1][v] = vd.y; eT[4*q+2][v] = vd.z; eT[4*q+3][v] = vd.w;
        }
        __syncthreads();
        #pragma unroll 4
        for (int k = 0; k < CKL; ++k) {
            float4 h0 = *(const float4*)&hL[k][8 * ty];
            float4 h1 = *(const float4*)&hL[k][8 * ty + 4];
            float4 e0 = *(const float4*)&eT[k][8 * tx];
            float4 e1 = *(const float4*)&eT[k][8 * tx + 4];
            float hv[8] = {h0.x, h0.y, h0.z, h0.w, h1.x, h1.y, h1.z, h1.w};
            float ev[8] = {e0.x, e0.y, e0.z, e0.w, e1.x, e1.y, e1.z, e1.w};
            #pragma unroll
            for (int j = 0; j < 8; ++j)
                #pragma unroll
                for (int i = 0; i < 8; ++i)
                    acc[j][i] += hv[j] * ev[i];
        }
        __syncthreads();
    }
    // epilogue: round to bf16, per-row partial max/expsum (16 tx lanes own one
    // row's 128 v), pack+store 8 bf16 per row as uint4.
    #pragma unroll
    for (int j = 0; j < 8; ++j) {
        int bt = 8 * ty + j;
        unsigned bb[8];
        float r[8];
        float m = -1e30f;
        #pragma unroll
        for (int i = 0; i < 8; ++i) {
            bb[i] = bf16rne(acc[j][i]);
            r[i] = __uint_as_float(bb[i] << 16);
            m = fmaxf(m, r[i]);
        }
        #pragma unroll
        for (int o = 8; o >= 1; o >>= 1) m = fmaxf(m, __shfl_xor(m, o, 16));
        float es = 0.0f;
        #pragma unroll
        for (int i = 0; i < 8; ++i) es += __expf(r[i] - m);
        #pragma unroll
        for (int o = 8; o >= 1; o >>= 1) es += __shfl_xor(es, o, 16);
        if (tx == 0) {
            pmax[bid * BTq + bt] = m;
            psum[bid * BTq + bt] = es;
        }
        uint4 w = make_uint4(bb[0] | (bb[1] << 16), bb[2] | (bb[3] << 16),
                             bb[4] | (bb[5] << 16), bb[6] | (bb[7] << 16));
        *(uint4*)(logits + (size_t)bt * Vq + v0 + 8 * tx) = w;
    }
}

// single streaming pass: finalize (m,s) from 250 partials; build the 4000-v
// chunk in LDS (pg*softmax), scatter-add (1-pg)*probs via story tokens (LDS
// atomics handle duplicates), then one coalesced nontemporal write. 1024 blocks.
__global__ __launch_bounds__(256) void k_final(const unsigned short* __restrict__ logits,
                                               const float* __restrict__ probs,
                                               const int* __restrict__ story,
                                               const float* __restrict__ pgen,
                                               const float* __restrict__ pmax,
                                               const float* __restrict__ psum,
                                               float* __restrict__ out) {
    __shared__ float chunk[FCH];                      // 16 KB
    __shared__ float red[4];
    int bid = blockIdx.x, tid = threadIdx.x;
    int bt = bid >> 3, ch = bid & 7, b = bt >> 3;
    float pm = (tid < NCOMPUTE) ? pmax[tid * BTq + bt] : -1e30f;
    float m = blockReduceMax(pm, red);
    float part = (tid < NCOMPUTE) ? psum[tid * BTq + bt] * __expf(pm - m) : 0.0f;
    float s = blockReduceSum(part, red);
    float inv = 1.0f / s, pg = pgen[bt], cg = 1.0f - pg;
    int lo = ch * FCH;
    const uint4* l4 = (const uint4*)(logits + (size_t)bt * Vq + lo);  // 500 uint4
    for (int i = tid; i < FCH / 8; i += 256) {
        uint4 lv = l4[i];
        float f0 = __uint_as_float(lv.x << 16), f1 = __uint_as_float(lv.x & 0xFFFF0000u);
        float f2 = __uint_as_float(lv.y << 16), f3 = __uint_as_float(lv.y & 0xFFFF0000u);
        float f4 = __uint_as_float(lv.z << 16), f5 = __uint_as_float(lv.z & 0xFFFF0000u);
        float f6 = __uint_as_float(lv.w << 16), f7 = __uint_as_float(lv.w & 0xFFFF0000u);
        chunk[8 * i + 0] = pg * __expf(f0 - m) * inv;
        chunk[8 * i + 1] = pg * __expf(f1 - m) * inv;
        chunk[8 * i + 2] = pg * __expf(f2 - m) * inv;
        chunk[8 * i + 3] = pg * __expf(f3 - m) * inv;
        chunk[8 * i + 4] = pg * __expf(f4 - m) * inv;
        chunk[8 * i + 5] = pg * __expf(f5 - m) * inv;
        chunk[8 * i + 6] = pg * __expf(f6 - m) * inv;
        chunk[8 * i + 7] = pg * __expf(f7 - m) * inv;
    }
    __syncthreads();
    for (int ss = tid; ss < Sq; ss += 256) {
        int rel = story[b * Sq + ss] - lo;
        if (rel >= 0 && rel < FCH)
            atomicAdd(&chunk[rel], cg * probs[bt * Sq + ss]);
    }
    __syncthreads();
    f4nt* o4 = (f4nt*)(out + (size_t)bt * Vq + lo);
    const f4nt* c4 = (const f4nt*)chunk;
    for (int i = tid; i < FCH / 4; i += 256)
        __builtin_nontemporal_store(c4[i], &o4[i]);
}

extern "C" void kernel_launch(void* const* d_in, const int* in_sizes, int n_in,
                              void* d_out, int out_size, void* d_ws, size_t ws_size,
                              hipStream_t stream) {
    const float* enc_hidden = (const float*)d_in[0];
    const float* enc_out    = (const float*)d_in[1];
    const int*   story      = (const int*)d_in[2];
    const int*   trg        = (const int*)d_in[3];
    const float* shared_emb = (const float*)d_in[4];
    const float* slot_emb   = (const float*)d_in[5];
    const float* w_ih       = (const float*)d_in[6];
    const float* w_hh       = (const float*)d_in[7];
    const float* b_ih       = (const float*)d_in[8];
    const float* b_hh       = (const float*)d_in[9];
    const float* w_ratio_w  = (const float*)d_in[10];
    const float* w_ratio_b  = (const float*)d_in[11];
    const float* w_gate_w   = (const float*)d_in[12];
    const float* w_gate_b   = (const float*)d_in[13];

    float* out = (float*)d_out;

    // All scratch in d_ws.
    float* ws = (float*)d_ws;
    unsigned short* logits_buf = (unsigned short*)ws;  // 4,096,000 bf16 (8.2 MB)
    float* probs_buf  = ws + (size_t)SLICE;        // 65,536 f (128 x 512)
    float* hT_buf     = ws + 2 * (size_t)SLICE;    // 51,200 f
    float* pgen_buf   = hT_buf + 51200;            // 128 f
    float* pmax_buf   = pgen_buf + 128;            // 32,000 f (250 x 128)
    float* psum_buf   = pmax_buf + 32000;          // 32,000 f

    hipLaunchKernelGGL(k_attn, dim3(BTq + AZB), dim3(512), 0, stream,
                       enc_hidden, shared_emb, slot_emb, w_ih, w_hh, b_ih, b_hh, trg,
                       enc_out, story, w_ratio_w, w_ratio_b, w_gate_w, w_gate_b,
                       probs_buf, pgen_buf, hT_buf, out + PTR_TOTAL, out);
    hipLaunchKernelGGL(k_logits, dim3(NCOMPUTE + LZB + 1), dim3(256), 0, stream,
                       hT_buf, shared_emb, logits_buf, pmax_buf, psum_buf, out);
    hipLaunchKernelGGL(k_final, dim3(BTq * FBLK), dim3(256), 0, stream,
                       logits_buf, probs_buf, story, pgen_buf, pmax_buf, psum_buf, out);
}